// Round 14
// baseline (256.382 us; speedup 1.0000x reference)
//
#include <hip/hip_runtime.h>
#include <hip/hip_cooperative_groups.h>
#include <hip/hip_fp8.h>
#include <stdint.h>
#include <stddef.h>

#define BATCH 8192
#define DIM   256

#define LN2F 0.6931471805599453f
// operand quantization scales; product = 1000*log2(e) = 1442.6950408889634
// so MFMA accs are directly exp2-domain scores (no dequant in hot loop).
#define SCALE_ZJ 16.0f                 // A side (staged)
#define SCALE_ZI 90.16844005556021f    // B side (regs)

typedef int   v4i    __attribute__((ext_vector_type(4)));
typedef int   v8i    __attribute__((ext_vector_type(8)));
typedef float f32x16 __attribute__((ext_vector_type(16)));

// Slot-tiled layout (tile = 32 rows x 256B = 8KB), verified R7-R11 (conflicts 0):
//   elem(row, kb) -> tile(row>>5)*8192 + q*2048 + c*1024 + (32h + (row&31))*16 + b
//   with kb = q*64 + h*32 + c*16 + b. Slot (32h+r32) == MFMA lane id.
// LAUNCH-BOUND RULE (R5/R7/R12/R13): any restrictive min-waves bound can make
// the allocator spill accs to scratch (100-300MB FETCH/WRITE, MfmaUtil<9%).
// This kernel runs 1 block/CU (64KB LDS) -> NO launch bound, allocator free.

// ---------- helpers ----------
static __device__ __forceinline__ uint8_t f2fp8(float f) {
  __hip_fp8_e4m3 q(f);                       // OCP e4m3fn, RNE+sat
  return *reinterpret_cast<uint8_t*>(&q);
}
static __device__ __forceinline__ v8i cat8(v4i lo, v4i hi) {
  return __builtin_shufflevector(lo, hi, 0, 1, 2, 3, 4, 5, 6, 7);
}

// online lse update for one 16-score acc block (verified R6-R11)
static __device__ __forceinline__ void lse_update(const f32x16& acc,
                                                  float& m, float& l) {
  float t0 = fmaxf(fmaxf(acc[0],  acc[1]),  acc[2]);
  float t1 = fmaxf(fmaxf(acc[3],  acc[4]),  acc[5]);
  float t2 = fmaxf(fmaxf(acc[6],  acc[7]),  acc[8]);
  float t3 = fmaxf(fmaxf(acc[9],  acc[10]), acc[11]);
  t0 = fmaxf(fmaxf(t0, t1), fmaxf(fmaxf(acc[12], acc[13]), acc[14]));
  t2 = fmaxf(fmaxf(t2, t3), acc[15]);
  const float mn = fmaxf(m, fmaxf(t0, t2));
  float s0 = 0.f, s1 = 0.f;
#pragma unroll
  for (int r = 0; r < 16; r += 2) {
    s0 += __builtin_amdgcn_exp2f(acc[r + 0] - mn);
    s1 += __builtin_amdgcn_exp2f(acc[r + 1] - mn);
  }
  l = l * __builtin_amdgcn_exp2f(m - mn) + (s0 + s1);
  m = mn;
}

// stage one 32KB sub-chunk: identity mapping, fully coalesced
static __device__ __forceinline__ void stage32k(const uint8_t* __restrict__ src,
                                                uint8_t* dst, int tid) {
#pragma unroll
  for (int it = 0; it < 8; ++it) {
    const int off = it * 4096 + tid * 16;
    __builtin_amdgcn_global_load_lds(
        (const __attribute__((address_space(1))) void*)(src + off),
        (__attribute__((address_space(3))) void*)(dst + off), 16, 0, 0);
  }
}

// ================= fused cooperative kernel: prep + lse + finalize =========
// grid = 256 blocks x 256 thr, 1 block/CU (64KB LDS). Three grid.sync()s.
__global__ void fused_kernel(const float* __restrict__ p1,
                             const float* __restrict__ p2,
                             uint8_t* __restrict__ Zi8, uint8_t* __restrict__ Zj8,
                             float* __restrict__ pos, float* __restrict__ plse,
                             float2* __restrict__ bpart, float* __restrict__ out) {
  cooperative_groups::grid_group grid = cooperative_groups::this_grid();
  const int bid  = blockIdx.x;
  const int tid  = threadIdx.x;
  const int lane = tid & 63;
  const int w    = tid >> 6;
  const int r32  = lane & 31;
  const int h    = lane >> 5;

  __shared__ __align__(16) uint8_t lds[65536];

  // ---------- phase A: normalize + quantize, LDS-transposed coalesced store
  {
    const int R0 = bid * 32;                 // this block owns one 32-row tile
#pragma unroll
    for (int p = 0; p < 8; ++p) {
      const int row = R0 + w * 8 + p;        // one row per wave-pass
      const float4 x1 = ((const float4*)p1)[row * 64 + lane];
      const float4 x2 = ((const float4*)p2)[row * 64 + lane];
      float ss1 = x1.x * x1.x + x1.y * x1.y + x1.z * x1.z + x1.w * x1.w;
      float ss2 = x2.x * x2.x + x2.y * x2.y + x2.z * x2.z + x2.w * x2.w;
      float d   = x1.x * x2.x + x1.y * x2.y + x1.z * x2.z + x1.w * x2.w;
#pragma unroll
      for (int m = 1; m < 64; m <<= 1) {
        ss1 += __shfl_xor(ss1, m);
        ss2 += __shfl_xor(ss2, m);
        d   += __shfl_xor(d, m);
      }
      const float n1 = fmaxf(sqrtf(ss1), 1e-12f);
      const float n2 = fmaxf(sqrtf(ss2), 1e-12f);
      if (lane == 0) pos[row] = d / (n1 * n2);   // exact fp32 diagonal
      const float sI = SCALE_ZI / n1;
      const float sJ = SCALE_ZJ / n2;
      uchar4 u1, u2;
      u1.x = f2fp8(x1.x * sI); u1.y = f2fp8(x1.y * sI);
      u1.z = f2fp8(x1.z * sI); u1.w = f2fp8(x1.w * sI);
      u2.x = f2fp8(x2.x * sJ); u2.y = f2fp8(x2.y * sJ);
      u2.z = f2fp8(x2.z * sJ); u2.w = f2fp8(x2.w * sJ);
      // scatter into LDS at the tiled offset (cheap), not into global
      const int off = (lane >> 4) * 2048 + ((lane >> 2) & 1) * 1024 +
                      (((lane >> 3) & 1) * 32 + (row & 31)) * 16 + (lane & 3) * 4;
      *(uchar4*)(lds + off) = u1;              // Zi tile at lds[0..8191]
      *(uchar4*)(lds + 8192 + off) = u2;       // Zj tile at lds[8192..16383]
    }
    __syncthreads();
    // coalesced 32B/thread tile stores
    const v4i a0 = *(const v4i*)(lds + tid * 32);
    const v4i a1 = *(const v4i*)(lds + tid * 32 + 16);
    const v4i b0_ = *(const v4i*)(lds + 8192 + tid * 32);
    const v4i b1_ = *(const v4i*)(lds + 8192 + tid * 32 + 16);
    *(v4i*)(Zi8 + (size_t)bid * 8192 + tid * 32)      = a0;
    *(v4i*)(Zi8 + (size_t)bid * 8192 + tid * 32 + 16) = a1;
    *(v4i*)(Zj8 + (size_t)bid * 8192 + tid * 32)      = b0_;
    *(v4i*)(Zj8 + (size_t)bid * 8192 + tid * 32 + 16) = b1_;
  }
  __threadfence();
  grid.sync();

  // ---------- phase B: fused fp8 MFMA GEMM + online logsumexp --------------
  // block = 256 i-rows x 1024 j-cols; rb = bid>>3, chunk = bid&7 (XCD-local Zj).
  // acc = mfma_scale_32x32x64(A=Zj, B=Zi) -> D[j][i], col(lane&31)=i; each
  // lane owns two i rows. 2x32KB LDS ring over 8 sub-chunks of 128 j-cols.
  {
    const int rb    = bid >> 3;
    const int chunk = bid & 7;
    const int iBase = rb * 256 + w * 64;
    const uint8_t* src = Zj8 + (size_t)chunk * 262144;

    stage32k(src, lds, tid);                  // prologue: sub-chunk 0

    v8i b0[4], b1[4];
    const uint8_t* zb = Zi8 + (size_t)(rb * 8 + w * 2) * 8192 + lane * 16;
#pragma unroll
    for (int q = 0; q < 4; ++q) {
      b0[q] = cat8(*(const v4i*)(zb + q * 2048),
                   *(const v4i*)(zb + q * 2048 + 1024));
      b1[q] = cat8(*(const v4i*)(zb + 8192 + q * 2048),
                   *(const v4i*)(zb + 8192 + q * 2048 + 1024));
    }
#pragma unroll
    for (int q = 0; q < 4; ++q) { asm("" : "+v"(b0[q])); asm("" : "+v"(b1[q])); }

    float m0 = -1e30f, l0 = 0.f, m1 = -1e30f, l1 = 0.f;

    for (int s = 0; s < 8; ++s) {
      __syncthreads();                        // sub-chunk s resident
      if (s < 7) stage32k(src + (size_t)(s + 1) * 32768,
                          lds + ((s + 1) & 1) * 32768, tid);
      const uint8_t* base = lds + (s & 1) * 32768;
#pragma unroll
      for (int t = 0; t < 4; ++t) {
        const uint8_t* buf = base + t * 8192 + lane * 16;
        f32x16 acc0 = {}, acc1 = {};
#pragma unroll
        for (int q = 0; q < 4; ++q) {
          const v8i av = cat8(*(const v4i*)(buf + q * 2048),
                              *(const v4i*)(buf + q * 2048 + 1024));
          acc0 = __builtin_amdgcn_mfma_scale_f32_32x32x64_f8f6f4(
              av, b0[q], acc0, 0, 0, 0, 0x7F7F7F7F, 0, 0x7F7F7F7F);
          acc1 = __builtin_amdgcn_mfma_scale_f32_32x32x64_f8f6f4(
              av, b1[q], acc1, 0, 0, 0, 0x7F7F7F7F, 0, 0x7F7F7F7F);
        }
        lse_update(acc0, m0, l0);
        lse_update(acc1, m1, l1);
      }
    }

    // lanes l and l+32 hold the same i with complementary j-subsets
#pragma unroll
    for (int p = 0; p < 2; ++p) {
      float m = p ? m1 : m0;
      float l = p ? l1 : l0;
      const float mo = __shfl_xor(m, 32);
      const float lo = __shfl_xor(l, 32);
      const float mn = fmaxf(m, mo);
      l = l * __builtin_amdgcn_exp2f(m - mn) +
          lo * __builtin_amdgcn_exp2f(mo - mn);
      if (h == 0) {
        const int i = iBase + p * 32 + r32;
        plse[(size_t)i * 8 + chunk] = mn + __builtin_amdgcn_logf(l);  // log2-lse
      }
    }
  }
  __threadfence();
  grid.sync();

  // ---------- phase C: per-row combine (8 chunks) + block partial ----------
  {
    const int row = bid * 32 + (tid >> 3);
    const int c   = tid & 7;
    const float v = plse[(size_t)row * 8 + c];
    float M = v;
#pragma unroll
    for (int msk = 1; msk < 8; msk <<= 1) M = fmaxf(M, __shfl_xor(M, msk));
    float S = __builtin_amdgcn_exp2f(v - M);
#pragma unroll
    for (int msk = 1; msk < 8; msk <<= 1) S += __shfl_xor(S, msk);
    float contrib = 0.f, pv = 0.f;
    if (c == 0) {
      pv = pos[row];
      contrib = LN2F * (M + __builtin_amdgcn_logf(S)) - 1000.0f * pv;
    }
#pragma unroll
    for (int msk = 1; msk < 64; msk <<= 1) {
      contrib += __shfl_xor(contrib, msk);
      pv      += __shfl_xor(pv, msk);
    }
    __syncthreads();   // lds reuse safe (phase B reads done block-wide)
    float* fl = (float*)lds;
    if (lane == 0) { fl[w] = contrib; fl[4 + w] = pv; }
    __syncthreads();
    if (tid == 0)
      bpart[bid] = make_float2(fl[0] + fl[1] + fl[2] + fl[3],
                               fl[4] + fl[5] + fl[6] + fl[7]);
  }
  __threadfence();
  grid.sync();

  // ---------- phase D: block 0 reduces 256 partials (deterministic) --------
  if (bid == 0) {
    const float2 bv = bpart[tid];
    float L = bv.x, P = bv.y;
#pragma unroll
    for (int msk = 1; msk < 64; msk <<= 1) {
      L += __shfl_xor(L, msk);
      P += __shfl_xor(P, msk);
    }
    float* fl = (float*)lds;
    if (lane == 0) { fl[8 + w] = L; fl[12 + w] = P; }
    __syncthreads();
    if (tid == 0) {
      out[0] = (fl[8] + fl[9] + fl[10] + fl[11]) / (float)BATCH;  // loss
      out[1] = fl[12] + fl[13] + fl[14] + fl[15];                 // sum(positives)
    }
  }
}

extern "C" void kernel_launch(void* const* d_in, const int* in_sizes, int n_in,
                              void* d_out, int out_size, void* d_ws, size_t ws_size,
                              hipStream_t stream) {
  const float* p1 = (const float*)d_in[0];
  const float* p2 = (const float*)d_in[1];
  float* out = (float*)d_out;
  uint8_t* ws = (uint8_t*)d_ws;

  uint8_t* Zi8   = ws;                                                   // 2 MB (tiled)
  uint8_t* Zj8   = ws + (size_t)2 * 1024 * 1024;                         // 2 MB (tiled)
  float*   pos   = (float*)(ws + (size_t)4 * 1024 * 1024);               // 32 KB
  float*   plse  = (float*)(ws + (size_t)4 * 1024 * 1024 + 32 * 1024);   // 256 KB
  float2*  bpart = (float2*)(ws + (size_t)4 * 1024 * 1024 + 320 * 1024); // 2 KB

  void* args[] = {(void*)&p1, (void*)&p2, (void*)&Zi8, (void*)&Zj8,
                  (void*)&pos, (void*)&plse, (void*)&bpart, (void*)&out};
  hipLaunchCooperativeKernel((const void*)fused_kernel, dim3(256), dim3(256),
                             args, 0, stream);
}